// Round 1
// baseline (722.146 us; speedup 1.0000x reference)
//
#include <hip/hip_runtime.h>

// SelectiveAttnMLA on MI355X (gfx950).
// B=4 S=2048 Hq=16 G=4 D=192 DV=128 BLK=64 NB=32 TOPK=16, out fp32 (8192x2048).
//
// Structure:
//  kf_prep: k fp32 [t][h][192] -> f16 B-fragments per (b,h,kb): frag order
//           [ntile(4)][kc(6)][lane(64)][8], element = K[n=ntile*16+(L&15)][d=kc*32+(L>>4)*8+j]
//  vf_prep: v fp32 -> f16 B-fragments per (b,h,kb): [n0(8)][kc(2)][lane][8],
//           element = V[k=kc*32+(L>>4)*8+j][dv=n0*16+(L&15)]   (LDS transpose)
//  attn_main: wave = 16 query rows x 1 head; online softmax in exp2 domain;
//           P relayout C->A through wave-private padded LDS; no barriers in loop.

typedef __attribute__((ext_vector_type(8))) _Float16 half8;
typedef __attribute__((ext_vector_type(4))) float f32x4;

__device__ __forceinline__ half8 cvt8(const float4* p) {
  float4 a = p[0], b = p[1];
  half8 r;
  r[0] = (_Float16)a.x; r[1] = (_Float16)a.y; r[2] = (_Float16)a.z; r[3] = (_Float16)a.w;
  r[4] = (_Float16)b.x; r[5] = (_Float16)b.y; r[6] = (_Float16)b.z; r[7] = (_Float16)b.w;
  return r;
}

// ---------------- K fragment prepass ----------------
// one thread per 16B octet; 4*16*32 blocks * 1536 octets = 3,145,728 threads
__global__ __launch_bounds__(256) void kf_prep(const float* __restrict__ k,
                                               _Float16* __restrict__ kf) {
  int O = blockIdx.x * 256 + threadIdx.x;
  int blk = O / 1536;                 // (b*16+h)*32 + kb
  int rem = O - blk * 1536;
  int frag = rem >> 6;                // ntile*6 + kc
  int lane = rem & 63;
  int ntile = frag / 6;
  int kc = frag - ntile * 6;
  int n = ntile * 16 + (lane & 15);
  int d = kc * 32 + (lane >> 4) * 8;
  int bh = blk >> 5, kb = blk & 31;
  int b = bh >> 4, h = bh & 15;
  long t = (long)b * 2048 + kb * 64 + n;
  const float* src = k + (t * 16 + h) * 192 + d;
  *(half8*)(kf + (long)O * 8) = cvt8((const float4*)src);
}

// ---------------- V fragment prepass (transpose via LDS) ----------------
__global__ __launch_bounds__(256) void vf_prep(const float* __restrict__ v,
                                               _Float16* __restrict__ vf) {
  __shared__ float ld[64][132];       // 64 keys x 128 dv, padded
  int blk = blockIdx.x;               // (b*16+h)*32 + kb
  int bh = blk >> 5, kb = blk & 31;
  int b = bh >> 4, h = bh & 15;
  int tid = threadIdx.x;
  const float* src = v + ((long)(b * 2048 + kb * 64) * 16 + h) * 128;
#pragma unroll
  for (int it = 0; it < 32; ++it) {
    int id = it * 256 + tid;
    int kk = id >> 7, dv = id & 127;
    ld[kk][dv] = src[(long)kk * 2048 + dv];
  }
  __syncthreads();
  _Float16* dst = vf + (long)blk * 8192;
#pragma unroll
  for (int it = 0; it < 4; ++it) {
    int oct = it * 256 + tid;         // 0..1023
    int frag = oct >> 6, lane = oct & 63;
    int n0 = frag >> 1, kc = frag & 1;
    int dv = n0 * 16 + (lane & 15);
    int kbase = kc * 32 + (lane >> 4) * 8;
    half8 o;
#pragma unroll
    for (int j = 0; j < 8; ++j) o[j] = (_Float16)ld[kbase + j][dv];
    *(half8*)(dst + (long)oct * 8) = o;
  }
}

// ---------------- main attention ----------------
__global__ __launch_bounds__(256) void attn_main(const float* __restrict__ q,
                                                 const int* __restrict__ idx,
                                                 const _Float16* __restrict__ kf,
                                                 const _Float16* __restrict__ vf,
                                                 float* __restrict__ out) {
  constexpr float SCL = 0.07216878364870322f * 1.4426950408889634f;  // sm_scale*log2e
  int qb = 31 - (int)blockIdx.x;      // big tiles first (load balance)
  int h = blockIdx.y, b = blockIdx.z, g = h >> 2;
  int tid = threadIdx.x;
  int w = tid >> 6, L = tid & 63;
  int Lm = L & 15, Lq = L >> 4;
  int m0 = w * 16;                    // wave's first row within 64-tile
  int t0 = b * 2048 + qb * 64;

  __shared__ __align__(16) _Float16 Pbuf[4][16 * 72];  // per-wave, stride 72 f16 = 144 B

  // Q A-fragments: A[m=Lm][k=c*32+Lq*8+j], query row t0+m0+Lm
  half8 qa[6];
  const float* qrow = q + ((long)(t0 + m0 + Lm) * 16 + h) * 192;
#pragma unroll
  for (int c = 0; c < 6; ++c) qa[c] = cvt8((const float4*)(qrow + c * 32 + Lq * 8));

  // per-row selected-block bitmask (dedups TOPK duplicates)
  unsigned mrow = 0;
  {
    const int* ip = idx + ((long)(t0 + m0 + Lm) * 4 + g) * 16;
#pragma unroll
    for (int j = 0; j < 16; ++j) mrow |= (1u << ip[j]);
  }
  unsigned un = mrow;
#pragma unroll
  for (int o = 32; o; o >>= 1) un |= __shfl_xor(un, o, 64);
  unsigned smask[4];
#pragma unroll
  for (int i = 0; i < 4; ++i) smask[i] = __shfl(mrow, Lq * 4 + i, 64);  // mask of C-row Lq*4+i

  f32x4 Oacc[8];
#pragma unroll
  for (int n0 = 0; n0 < 8; ++n0) Oacc[n0] = (f32x4){0.f, 0.f, 0.f, 0.f};
  float m_i[4] = {-1e30f, -1e30f, -1e30f, -1e30f};
  float l_i[4] = {0.f, 0.f, 0.f, 0.f};

  const _Float16* kfb = kf + (long)((b * 16 + h) * 32) * 12288;
  const _Float16* vfb = vf + (long)((b * 16 + h) * 32) * 8192;
  _Float16* pw = &Pbuf[w][0];

  for (int kb = 0; kb <= qb; ++kb) {
    if (!((un >> kb) & 1u)) continue;  // wave-uniform skip
    const half8* kfrag = (const half8*)(kfb + (long)kb * 12288);
    const half8* vfrag = (const half8*)(vfb + (long)kb * 8192);

    // S = Q K^T : 16 rows x 64 keys
    f32x4 S[4];
#pragma unroll
    for (int nt = 0; nt < 4; ++nt) {
      f32x4 acc = {0.f, 0.f, 0.f, 0.f};
#pragma unroll
      for (int c = 0; c < 6; ++c)
        acc = __builtin_amdgcn_mfma_f32_16x16x32_f16(qa[c], kfrag[(nt * 6 + c) * 64 + L], acc, 0, 0, 0);
      S[nt] = acc;
    }

    bool lastb = (kb == qb);
    float rmax[4] = {-1e30f, -1e30f, -1e30f, -1e30f};
    float sc[4][4];
#pragma unroll
    for (int nt = 0; nt < 4; ++nt) {
      int key = nt * 16 + Lm;
#pragma unroll
      for (int i = 0; i < 4; ++i) {
        bool ok = ((smask[i] >> kb) & 1u) && (!lastb || key <= m0 + Lq * 4 + i);
        float val = ok ? S[nt][i] * SCL : -1e30f;
        sc[nt][i] = val;
        rmax[i] = fmaxf(rmax[i], val);
      }
    }
#pragma unroll
    for (int i = 0; i < 4; ++i) {
      float r = rmax[i];
      r = fmaxf(r, __shfl_xor(r, 1, 64));
      r = fmaxf(r, __shfl_xor(r, 2, 64));
      r = fmaxf(r, __shfl_xor(r, 4, 64));
      r = fmaxf(r, __shfl_xor(r, 8, 64));
      rmax[i] = r;
    }
    float alpha[4], psum[4];
    _Float16 pf[4][4];
#pragma unroll
    for (int i = 0; i < 4; ++i) {
      float mn = fmaxf(m_i[i], rmax[i]);
      alpha[i] = exp2f(m_i[i] - mn);
      m_i[i] = mn;
      float s = 0.f;
#pragma unroll
      for (int nt = 0; nt < 4; ++nt) {
        float p = exp2f(sc[nt][i] - mn);
        pf[nt][i] = (_Float16)p;
        s += p;
      }
      psum[i] = s;
    }
#pragma unroll
    for (int i = 0; i < 4; ++i) {
      float s = psum[i];
      s += __shfl_xor(s, 1, 64);
      s += __shfl_xor(s, 2, 64);
      s += __shfl_xor(s, 4, 64);
      s += __shfl_xor(s, 8, 64);
      l_i[i] = l_i[i] * alpha[i] + s;
    }
#pragma unroll
    for (int n0 = 0; n0 < 8; ++n0)
#pragma unroll
      for (int i = 0; i < 4; ++i) Oacc[n0][i] *= alpha[i];

    // P: C-layout -> LDS [row][key] (stride 72 f16), then read as A-fragments.
    asm volatile("s_waitcnt lgkmcnt(0)" ::: "memory");  // WAR vs last iter's reads
#pragma unroll
    for (int nt = 0; nt < 4; ++nt)
#pragma unroll
      for (int i = 0; i < 4; ++i)
        pw[(Lq * 4 + i) * 72 + nt * 16 + Lm] = pf[nt][i];
    asm volatile("s_waitcnt lgkmcnt(0)" ::: "memory");  // RAW: writes visible

#pragma unroll
    for (int kc = 0; kc < 2; ++kc) {
      half8 afr = *(const half8*)(pw + Lm * 72 + kc * 32 + Lq * 8);  // 16B-aligned
#pragma unroll
      for (int n0 = 0; n0 < 8; ++n0)
        Oacc[n0] = __builtin_amdgcn_mfma_f32_16x16x32_f16(afr, vfrag[(n0 * 2 + kc) * 64 + L], Oacc[n0], 0, 0, 0);
    }
  }

#pragma unroll
  for (int i = 0; i < 4; ++i) l_i[i] = 1.f / l_i[i];
  float* orow = out + (long)(t0 + m0 + Lq * 4) * 2048 + h * 128 + Lm;
#pragma unroll
  for (int i = 0; i < 4; ++i)
#pragma unroll
    for (int n0 = 0; n0 < 8; ++n0)
      orow[(long)i * 2048 + n0 * 16] = Oacc[n0][i] * l_i[i];
}

extern "C" void kernel_launch(void* const* d_in, const int* in_sizes, int n_in,
                              void* d_out, int out_size, void* d_ws, size_t ws_size,
                              hipStream_t stream) {
  const float* q = (const float*)d_in[0];
  const float* k = (const float*)d_in[1];
  const float* v = (const float*)d_in[2];
  const int* idx = (const int*)d_in[3];
  _Float16* kf = (_Float16*)d_ws;                       // 4*16*32*12288 f16 = 50.3 MB
  _Float16* vf = kf + (size_t)4 * 16 * 32 * 12288;      // 4*16*32*8192  f16 = 33.6 MB
  float* out = (float*)d_out;
  kf_prep<<<12288, 256, 0, stream>>>(k, kf);
  vf_prep<<<2048, 256, 0, stream>>>(v, vf);
  attn_main<<<dim3(32, 16, 4), 256, 0, stream>>>(q, idx, kf, vf, out);
}

// Round 2
// 452.646 us; speedup vs baseline: 1.5954x; 1.5954x over previous
//
#include <hip/hip_runtime.h>

// SelectiveAttnMLA on MI355X (gfx950).
// B=4 S=2048 Hq=16 G=4 D=192 DV=128 BLK=64 NB=32 TOPK=16, out fp32 (8192x2048).
//
// R2: LDS-staged K/V fragments shared by all 4 waves (global_load_lds w=16),
//     DPP softmax reductions (no ds_bpermute in loop), qb swizzle for balance,
//     SM_SCALE*log2e folded into Q fragments.

typedef __attribute__((ext_vector_type(8))) _Float16 half8;
typedef __attribute__((ext_vector_type(4))) float f32x4;

__device__ __forceinline__ half8 cvt8(const float4* p) {
  float4 a = p[0], b = p[1];
  half8 r;
  r[0] = (_Float16)a.x; r[1] = (_Float16)a.y; r[2] = (_Float16)a.z; r[3] = (_Float16)a.w;
  r[4] = (_Float16)b.x; r[5] = (_Float16)b.y; r[6] = (_Float16)b.z; r[7] = (_Float16)b.w;
  return r;
}

__device__ __forceinline__ half8 cvt8s(const float4* p, float s) {
  float4 a = p[0], b = p[1];
  half8 r;
  r[0] = (_Float16)(a.x * s); r[1] = (_Float16)(a.y * s);
  r[2] = (_Float16)(a.z * s); r[3] = (_Float16)(a.w * s);
  r[4] = (_Float16)(b.x * s); r[5] = (_Float16)(b.y * s);
  r[6] = (_Float16)(b.z * s); r[7] = (_Float16)(b.w * s);
  return r;
}

__device__ __forceinline__ void async16(const void* g, void* l) {
  __builtin_amdgcn_global_load_lds(
      (const __attribute__((address_space(1))) void*)g,
      (__attribute__((address_space(3))) void*)l, 16, 0, 0);
}

// DPP lane permute within 16-lane rows. xor1=quad_perm(1,0,3,2)=0xB1,
// xor2=quad_perm(2,3,0,1)=0x4E, xor4-equiv=row_half_mirror=0x141,
// xor8-equiv=row_mirror=0x140 (valid for butterfly reduce: groups uniform
// after each step).
template <int CTRL>
__device__ __forceinline__ float dpp_mov(float x) {
  union { float f; int i; } u;
  u.f = x;
  u.i = __builtin_amdgcn_update_dpp(u.i, u.i, CTRL, 0xf, 0xf, true);
  return u.f;
}
__device__ __forceinline__ float row16_max(float r) {
  r = fmaxf(r, dpp_mov<0xB1>(r));
  r = fmaxf(r, dpp_mov<0x4E>(r));
  r = fmaxf(r, dpp_mov<0x141>(r));
  r = fmaxf(r, dpp_mov<0x140>(r));
  return r;
}
__device__ __forceinline__ float row16_sum(float r) {
  r += dpp_mov<0xB1>(r);
  r += dpp_mov<0x4E>(r);
  r += dpp_mov<0x141>(r);
  r += dpp_mov<0x140>(r);
  return r;
}

// ---------------- K fragment prepass ----------------
__global__ __launch_bounds__(256) void kf_prep(const float* __restrict__ k,
                                               _Float16* __restrict__ kf) {
  int O = blockIdx.x * 256 + threadIdx.x;
  int blk = O / 1536;                 // (b*16+h)*32 + kb
  int rem = O - blk * 1536;
  int frag = rem >> 6;                // ntile*6 + kc
  int lane = rem & 63;
  int ntile = frag / 6;
  int kc = frag - ntile * 6;
  int n = ntile * 16 + (lane & 15);
  int d = kc * 32 + (lane >> 4) * 8;
  int bh = blk >> 5, kb = blk & 31;
  int b = bh >> 4, h = bh & 15;
  long t = (long)b * 2048 + kb * 64 + n;
  const float* src = k + (t * 16 + h) * 192 + d;
  *(half8*)(kf + (long)O * 8) = cvt8((const float4*)src);
}

// ---------------- V fragment prepass (transpose via LDS) ----------------
__global__ __launch_bounds__(256) void vf_prep(const float* __restrict__ v,
                                               _Float16* __restrict__ vf) {
  __shared__ float ld[64][132];
  int blk = blockIdx.x;               // (b*16+h)*32 + kb
  int bh = blk >> 5, kb = blk & 31;
  int b = bh >> 4, h = bh & 15;
  int tid = threadIdx.x;
  const float* src = v + ((long)(b * 2048 + kb * 64) * 16 + h) * 128;
#pragma unroll
  for (int it = 0; it < 32; ++it) {
    int id = it * 256 + tid;
    int kk = id >> 7, dv = id & 127;
    ld[kk][dv] = src[(long)kk * 2048 + dv];
  }
  __syncthreads();
  _Float16* dst = vf + (long)blk * 8192;
#pragma unroll
  for (int it = 0; it < 4; ++it) {
    int oct = it * 256 + tid;
    int frag = oct >> 6, lane = oct & 63;
    int n0 = frag >> 1, kc = frag & 1;
    int dv = n0 * 16 + (lane & 15);
    int kbase = kc * 32 + (lane >> 4) * 8;
    half8 o;
#pragma unroll
    for (int j = 0; j < 8; ++j) o[j] = (_Float16)ld[kbase + j][dv];
    *(half8*)(dst + (long)oct * 8) = o;
  }
}

// ---------------- main attention ----------------
__global__ __launch_bounds__(256) void attn_main(const float* __restrict__ q,
                                                 const int* __restrict__ idx,
                                                 const _Float16* __restrict__ kf,
                                                 const _Float16* __restrict__ vf,
                                                 float* __restrict__ out) {
  constexpr float SCL = 0.07216878364870322f * 1.4426950408889634f;  // sm_scale*log2e
  // swizzle: id = (u<<6)|(b<<4)|h, qb = 31-u  -> each CU sees mixed qb,
  // fixed (b,h) under round-robin dispatch (L2-local kf/vf region).
  int id = (int)blockIdx.x;
  int qb = 31 - (id >> 6);
  int h = id & 15, b = (id >> 4) & 3, g = h >> 2;
  int tid = threadIdx.x;
  int w = tid >> 6, L = tid & 63;
  int Lm = L & 15, Lq = L >> 4;
  int m0 = w * 16;
  int t0 = b * 2048 + qb * 64;

  __shared__ __align__(16) char sh_kv[40960];          // 24KB K frags + 16KB V frags
  __shared__ __align__(16) _Float16 Pbuf[4][16 * 72];  // per-wave, stride 144B
  __shared__ unsigned un_sh[4];
  char* lk = sh_kv;
  char* lv = sh_kv + 24576;

  // Q A-fragments, pre-scaled by sm_scale*log2e
  half8 qa[6];
  const float* qrow = q + ((long)(t0 + m0 + Lm) * 16 + h) * 192;
#pragma unroll
  for (int c = 0; c < 6; ++c) qa[c] = cvt8s((const float4*)(qrow + c * 32 + Lq * 8), SCL);

  // per-row selected-block bitmask (dedups TOPK duplicates)
  unsigned mrow = 0;
  {
    const int* ip = idx + ((long)(t0 + m0 + Lm) * 4 + g) * 16;
#pragma unroll
    for (int j = 0; j < 16; ++j) mrow |= (1u << ip[j]);
  }
  unsigned un = mrow;
#pragma unroll
  for (int o = 32; o; o >>= 1) un |= __shfl_xor(un, o, 64);
  unsigned smask[4];
#pragma unroll
  for (int i = 0; i < 4; ++i) smask[i] = __shfl(mrow, Lq * 4 + i, 64);
  if (L == 0) un_sh[w] = un;
  __syncthreads();
  unsigned bm = un_sh[0] | un_sh[1] | un_sh[2] | un_sh[3];  // block union

  f32x4 Oacc[8];
#pragma unroll
  for (int n0 = 0; n0 < 8; ++n0) Oacc[n0] = (f32x4){0.f, 0.f, 0.f, 0.f};
  float m_i[4] = {-1e30f, -1e30f, -1e30f, -1e30f};
  float l_i[4] = {0.f, 0.f, 0.f, 0.f};

  const char* kfb = (const char*)(kf + (long)((b * 16 + h) * 32) * 12288);
  const char* vfb = (const char*)(vf + (long)((b * 16 + h) * 32) * 8192);
  _Float16* pw = &Pbuf[w][0];
  const half8* lkf = (const half8*)lk;
  const half8* lvf = (const half8*)lv;

  // kb MUST ascend: block 0 is guaranteed selected for every row, so m_i is
  // finite before any all-masked block (else exp2(-1e30 - -1e30) = 1 bug).
  for (int kb = 0; kb <= qb; ++kb) {
    if (!((bm >> kb) & 1u)) continue;  // block-uniform skip

    // stage K/V fragments for this kb: 40KB split across 4 waves
    {
      const char* kg = kfb + (long)kb * 24576;
      const char* vg = vfb + (long)kb * 16384;
#pragma unroll
      for (int c = 0; c < 6; ++c) {
        int ch = w + c * 4;            // 24 K chunks of 1KB
        async16(kg + ch * 1024 + L * 16, lk + ch * 1024);
      }
#pragma unroll
      for (int c = 0; c < 4; ++c) {
        int ch = w + c * 4;            // 16 V chunks of 1KB
        async16(vg + ch * 1024 + L * 16, lv + ch * 1024);
      }
    }
    asm volatile("s_waitcnt vmcnt(0)" ::: "memory");
    __syncthreads();

    if ((un >> kb) & 1u) {             // wave-uniform: any of my 16 rows selected
      // S = Q K^T : 16 rows x 64 keys (already in log2 domain via qa scale)
      f32x4 S[4];
#pragma unroll
      for (int nt = 0; nt < 4; ++nt) {
        f32x4 acc = {0.f, 0.f, 0.f, 0.f};
#pragma unroll
        for (int c = 0; c < 6; ++c)
          acc = __builtin_amdgcn_mfma_f32_16x16x32_f16(qa[c], lkf[(nt * 6 + c) * 64 + L], acc, 0, 0, 0);
        S[nt] = acc;
      }

      bool lastb = (kb == qb);
      float rmax[4] = {-1e30f, -1e30f, -1e30f, -1e30f};
      float sc[4][4];
#pragma unroll
      for (int nt = 0; nt < 4; ++nt) {
        int key = nt * 16 + Lm;
#pragma unroll
        for (int i = 0; i < 4; ++i) {
          bool ok = ((smask[i] >> kb) & 1u) && (!lastb || key <= m0 + Lq * 4 + i);
          float val = ok ? S[nt][i] : -1e30f;
          sc[nt][i] = val;
          rmax[i] = fmaxf(rmax[i], val);
        }
      }
      float alpha[4], psum[4];
      _Float16 pf[4][4];
#pragma unroll
      for (int i = 0; i < 4; ++i) {
        float r = row16_max(rmax[i]);
        float mn = fmaxf(m_i[i], r);
        alpha[i] = exp2f(m_i[i] - mn);
        m_i[i] = mn;
        float s = 0.f;
#pragma unroll
        for (int nt = 0; nt < 4; ++nt) {
          float p = exp2f(sc[nt][i] - mn);
          pf[nt][i] = (_Float16)p;
          s += p;
        }
        psum[i] = s;
      }
#pragma unroll
      for (int i = 0; i < 4; ++i) l_i[i] = l_i[i] * alpha[i] + row16_sum(psum[i]);
#pragma unroll
      for (int n0 = 0; n0 < 8; ++n0)
#pragma unroll
        for (int i = 0; i < 4; ++i) Oacc[n0][i] *= alpha[i];

      // P: C-layout -> LDS [row][key] (stride 72 f16), then read as A-fragments.
      asm volatile("s_waitcnt lgkmcnt(0)" ::: "memory");  // WAR vs last iter's reads
#pragma unroll
      for (int nt = 0; nt < 4; ++nt)
#pragma unroll
        for (int i = 0; i < 4; ++i)
          pw[(Lq * 4 + i) * 72 + nt * 16 + Lm] = pf[nt][i];
      asm volatile("s_waitcnt lgkmcnt(0)" ::: "memory");  // RAW: writes visible

#pragma unroll
      for (int kc = 0; kc < 2; ++kc) {
        half8 afr = *(const half8*)(pw + Lm * 72 + kc * 32 + Lq * 8);
#pragma unroll
        for (int n0 = 0; n0 < 8; ++n0)
          Oacc[n0] = __builtin_amdgcn_mfma_f32_16x16x32_f16(afr, lvf[(n0 * 2 + kc) * 64 + L], Oacc[n0], 0, 0, 0);
      }
    }
    __syncthreads();                   // protect LDS K/V reuse next iter
  }

#pragma unroll
  for (int i = 0; i < 4; ++i) l_i[i] = 1.f / l_i[i];
  float* orow = out + (long)(t0 + m0 + Lq * 4) * 2048 + h * 128 + Lm;
#pragma unroll
  for (int i = 0; i < 4; ++i)
#pragma unroll
    for (int n0 = 0; n0 < 8; ++n0)
      orow[(long)i * 2048 + n0 * 16] = Oacc[n0][i] * l_i[i];
}

extern "C" void kernel_launch(void* const* d_in, const int* in_sizes, int n_in,
                              void* d_out, int out_size, void* d_ws, size_t ws_size,
                              hipStream_t stream) {
  const float* q = (const float*)d_in[0];
  const float* k = (const float*)d_in[1];
  const float* v = (const float*)d_in[2];
  const int* idx = (const int*)d_in[3];
  _Float16* kf = (_Float16*)d_ws;                       // 4*16*32*12288 f16 = 50.3 MB
  _Float16* vf = kf + (size_t)4 * 16 * 32 * 12288;      // 4*16*32*8192  f16 = 33.6 MB
  float* out = (float*)d_out;
  kf_prep<<<12288, 256, 0, stream>>>(k, kf);
  vf_prep<<<2048, 256, 0, stream>>>(v, vf);
  attn_main<<<2048, 256, 0, stream>>>(q, idx, kf, vf, out);
}

// Round 3
// 409.009 us; speedup vs baseline: 1.7656x; 1.1067x over previous
//
#include <hip/hip_runtime.h>

// SelectiveAttnMLA on MI355X (gfx950).
// B=4 S=2048 Hq=16 G=4 D=192 DV=128 BLK=64 NB=32 TOPK=16, out fp32 (8192x2048).
//
// R3: fused coalesced K/V prepass (was ~226us hidden cost, scattered reads);
//     attn VALU diet: builtin exp2, causal iteration split out of main loop,
//     per-row 0/1 mask-multiply instead of per-element cndmask (shift-invariant
//     softmax makes inflated row-max exact), skip rescale when max unchanged.

typedef __attribute__((ext_vector_type(8))) _Float16 half8;
typedef __attribute__((ext_vector_type(4))) float f32x4;

__device__ __forceinline__ half8 cvt8(const float4* p) {
  float4 a = p[0], b = p[1];
  half8 r;
  r[0] = (_Float16)a.x; r[1] = (_Float16)a.y; r[2] = (_Float16)a.z; r[3] = (_Float16)a.w;
  r[4] = (_Float16)b.x; r[5] = (_Float16)b.y; r[6] = (_Float16)b.z; r[7] = (_Float16)b.w;
  return r;
}

__device__ __forceinline__ half8 cvt8s(const float4* p, float s) {
  float4 a = p[0], b = p[1];
  half8 r;
  r[0] = (_Float16)(a.x * s); r[1] = (_Float16)(a.y * s);
  r[2] = (_Float16)(a.z * s); r[3] = (_Float16)(a.w * s);
  r[4] = (_Float16)(b.x * s); r[5] = (_Float16)(b.y * s);
  r[6] = (_Float16)(b.z * s); r[7] = (_Float16)(b.w * s);
  return r;
}

__device__ __forceinline__ void async16(const void* g, void* l) {
  __builtin_amdgcn_global_load_lds(
      (const __attribute__((address_space(1))) void*)g,
      (__attribute__((address_space(3))) void*)l, 16, 0, 0);
}

// DPP butterfly within 16-lane rows (groups uniform after each step).
template <int CTRL>
__device__ __forceinline__ float dpp_mov(float x) {
  union { float f; int i; } u;
  u.f = x;
  u.i = __builtin_amdgcn_update_dpp(u.i, u.i, CTRL, 0xf, 0xf, true);
  return u.f;
}
__device__ __forceinline__ float row16_max(float r) {
  r = fmaxf(r, dpp_mov<0xB1>(r));   // quad_perm xor1
  r = fmaxf(r, dpp_mov<0x4E>(r));   // quad_perm xor2
  r = fmaxf(r, dpp_mov<0x141>(r));  // row_half_mirror
  r = fmaxf(r, dpp_mov<0x140>(r));  // row_mirror
  return r;
}
__device__ __forceinline__ float row16_sum(float r) {
  r += dpp_mov<0xB1>(r);
  r += dpp_mov<0x4E>(r);
  r += dpp_mov<0x141>(r);
  r += dpp_mov<0x140>(r);
  return r;
}

// ---------------- fused K/V fragment prepass ----------------
// one block per (b,h,kb): coalesced global reads through LDS, coalesced
// 16B fragment writes. Replaces kf_prep's 128B-at-12KB-stride reads.
__global__ __launch_bounds__(256) void kv_prep(const float* __restrict__ k,
                                               const float* __restrict__ v,
                                               _Float16* __restrict__ kf,
                                               _Float16* __restrict__ vf) {
  __shared__ float lb[64 * 196];      // K phase: [64][196]; V phase: [64][132]
  int blk = blockIdx.x;               // (b*16+h)*32 + kb
  int bh = blk >> 5, kb = blk & 31;
  int b = bh >> 4, h = bh & 15;
  int tid = threadIdx.x;

  // ---- K: load 64 rows x 192 f32, coalesced ----
  const float* ksrc = k + ((long)(b * 2048 + kb * 64) * 16 + h) * 192;
#pragma unroll
  for (int it = 0; it < 12; ++it) {
    int idx = it * 256 + tid;         // 3072 float4
    int kk = idx / 48, c4 = idx - kk * 48;
    *(float4*)(&lb[kk * 196 + c4 * 4]) = *(const float4*)(ksrc + (long)kk * 3072 + c4 * 4);
  }
  __syncthreads();
  _Float16* kdst = kf + (long)blk * 12288;
#pragma unroll
  for (int it = 0; it < 6; ++it) {
    int oct = it * 256 + tid;         // 1536 octets
    int frag = oct >> 6, lane = oct & 63;
    int ntile = frag / 6, kc = frag - ntile * 6;
    int n = ntile * 16 + (lane & 15);
    int d = kc * 32 + ((lane >> 4) << 3);
    *(half8*)(kdst + (long)oct * 8) = cvt8((const float4*)(&lb[n * 196 + d]));
  }
  __syncthreads();

  // ---- V: load 64 rows x 128 f32, coalesced; emit transposed frags ----
  const float* vsrc = v + ((long)(b * 2048 + kb * 64) * 16 + h) * 128;
#pragma unroll
  for (int it = 0; it < 8; ++it) {
    int idx = it * 256 + tid;         // 2048 float4
    int kk = idx >> 5, c4 = idx & 31;
    *(float4*)(&lb[kk * 132 + c4 * 4]) = *(const float4*)(vsrc + (long)kk * 2048 + c4 * 4);
  }
  __syncthreads();
  _Float16* vdst = vf + (long)blk * 8192;
#pragma unroll
  for (int it = 0; it < 4; ++it) {
    int oct = it * 256 + tid;         // 1024 octets
    int frag = oct >> 6, lane = oct & 63;
    int n0 = frag >> 1, kc = frag & 1;
    int dv = n0 * 16 + (lane & 15);
    int kbase = kc * 32 + ((lane >> 4) << 3);
    half8 o;
#pragma unroll
    for (int j = 0; j < 8; ++j) o[j] = (_Float16)lb[(kbase + j) * 132 + dv];
    *(half8*)(vdst + (long)oct * 8) = o;
  }
}

// ---------------- main attention ----------------
__global__ __launch_bounds__(256) void attn_main(const float* __restrict__ q,
                                                 const int* __restrict__ idx,
                                                 const _Float16* __restrict__ kf,
                                                 const _Float16* __restrict__ vf,
                                                 float* __restrict__ out) {
  constexpr float SCL = 0.07216878364870322f * 1.4426950408889634f;  // sm_scale*log2e
  int id = (int)blockIdx.x;
  int qb = 31 - (id >> 6);            // qb swizzle: CU gets mixed qb, fixed (b,h)
  int h = id & 15, b = (id >> 4) & 3, g = h >> 2;
  int tid = threadIdx.x;
  int w = tid >> 6, L = tid & 63;
  int Lm = L & 15, Lq = L >> 4;
  int m0 = w * 16;
  int t0 = b * 2048 + qb * 64;

  __shared__ __align__(16) char sh_kv[40960];          // 24KB K + 16KB V frags
  __shared__ __align__(16) _Float16 Pbuf[4][16 * 72];  // per-wave, stride 144B
  __shared__ unsigned un_sh[4];
  char* lk = sh_kv;
  char* lv = sh_kv + 24576;

  half8 qa[6];
  const float* qrow = q + ((long)(t0 + m0 + Lm) * 16 + h) * 192;
#pragma unroll
  for (int c = 0; c < 6; ++c) qa[c] = cvt8s((const float4*)(qrow + c * 32 + Lq * 8), SCL);

  unsigned mrow = 0;
  {
    const int* ip = idx + ((long)(t0 + m0 + Lm) * 4 + g) * 16;
#pragma unroll
    for (int j = 0; j < 16; ++j) mrow |= (1u << ip[j]);
  }
  unsigned un = mrow;
#pragma unroll
  for (int o = 32; o; o >>= 1) un |= __shfl_xor(un, o, 64);
  unsigned smask[4];
#pragma unroll
  for (int i = 0; i < 4; ++i) smask[i] = __shfl(mrow, Lq * 4 + i, 64);
  if (L == 0) un_sh[w] = un;
  __syncthreads();
  unsigned bm = un_sh[0] | un_sh[1] | un_sh[2] | un_sh[3];

  f32x4 Oacc[8];
#pragma unroll
  for (int n0 = 0; n0 < 8; ++n0) Oacc[n0] = (f32x4){0.f, 0.f, 0.f, 0.f};
  float m_i[4] = {-1e30f, -1e30f, -1e30f, -1e30f};
  float l_i[4] = {0.f, 0.f, 0.f, 0.f};

  const char* kfb = (const char*)(kf + (long)((b * 16 + h) * 32) * 12288);
  const char* vfb = (const char*)(vf + (long)((b * 16 + h) * 32) * 8192);
  _Float16* pw = &Pbuf[w][0];
  const half8* lkf = (const half8*)lk;
  const half8* lvf = (const half8*)lv;

  auto stage = [&](int kb) {
    const char* kg = kfb + (long)kb * 24576;
    const char* vg = vfb + (long)kb * 16384;
#pragma unroll
    for (int c = 0; c < 6; ++c) {
      int ch = w + c * 4;
      async16(kg + ch * 1024 + L * 16, lk + ch * 1024);
    }
#pragma unroll
    for (int c = 0; c < 4; ++c) {
      int ch = w + c * 4;
      async16(vg + ch * 1024 + L * 16, lv + ch * 1024);
    }
  };

  auto compute = [&](int kb, bool lastb) __attribute__((always_inline)) {
    // S = Q K^T (log2 domain via qa scale)
    f32x4 S[4];
#pragma unroll
    for (int nt = 0; nt < 4; ++nt) {
      f32x4 acc = {0.f, 0.f, 0.f, 0.f};
#pragma unroll
      for (int c = 0; c < 6; ++c)
        acc = __builtin_amdgcn_mfma_f32_16x16x32_f16(qa[c], lkf[(nt * 6 + c) * 64 + L], acc, 0, 0, 0);
      S[nt] = acc;
    }

    _Float16 pf[4][4];
    if (!lastb) {
      // no causal here; selection via per-row 0/1 multiply. Inflated row-max
      // from unselected rows is exact (softmax shift-invariance), p*0 kills it.
      float msel[4];
#pragma unroll
      for (int i = 0; i < 4; ++i) msel[i] = ((smask[i] >> kb) & 1u) ? 1.0f : 0.0f;
      float rmax[4] = {-1e30f, -1e30f, -1e30f, -1e30f};
#pragma unroll
      for (int nt = 0; nt < 4; ++nt)
#pragma unroll
        for (int i = 0; i < 4; ++i) rmax[i] = fmaxf(rmax[i], S[nt][i]);
#pragma unroll
      for (int i = 0; i < 4; ++i) rmax[i] = row16_max(rmax[i]);
      bool up = (rmax[0] > m_i[0]) | (rmax[1] > m_i[1]) |
                (rmax[2] > m_i[2]) | (rmax[3] > m_i[3]);
      if (__any(up)) {
        f32x4 av;
#pragma unroll
        for (int i = 0; i < 4; ++i) {
          float mn = fmaxf(m_i[i], rmax[i]);
          av[i] = __builtin_amdgcn_exp2f(m_i[i] - mn);
          m_i[i] = mn;
          l_i[i] *= av[i];
        }
#pragma unroll
        for (int n0 = 0; n0 < 8; ++n0) Oacc[n0] *= av;
      }
      float psum[4] = {0.f, 0.f, 0.f, 0.f};
#pragma unroll
      for (int nt = 0; nt < 4; ++nt)
#pragma unroll
        for (int i = 0; i < 4; ++i) {
          float p = __builtin_amdgcn_exp2f(S[nt][i] - m_i[i]) * msel[i];
          pf[nt][i] = (_Float16)p;
          psum[i] += p;
        }
#pragma unroll
      for (int i = 0; i < 4; ++i) l_i[i] += row16_sum(psum[i]);
    } else {
      // diagonal block: full per-element causal+selection masking
      float rmax[4] = {-1e30f, -1e30f, -1e30f, -1e30f};
      float sc[4][4];
#pragma unroll
      for (int nt = 0; nt < 4; ++nt) {
        int key = nt * 16 + Lm;
#pragma unroll
        for (int i = 0; i < 4; ++i) {
          bool ok = ((smask[i] >> kb) & 1u) && (key <= m0 + Lq * 4 + i);
          float val = ok ? S[nt][i] : -1e30f;
          sc[nt][i] = val;
          rmax[i] = fmaxf(rmax[i], val);
        }
      }
      f32x4 av;
      float psum[4];
#pragma unroll
      for (int i = 0; i < 4; ++i) {
        float r = row16_max(rmax[i]);
        float mn = fmaxf(m_i[i], r);
        av[i] = __builtin_amdgcn_exp2f(m_i[i] - mn);
        m_i[i] = mn;
        float s = 0.f;
#pragma unroll
        for (int nt = 0; nt < 4; ++nt) {
          float p = __builtin_amdgcn_exp2f(sc[nt][i] - mn);
          pf[nt][i] = (_Float16)p;
          s += p;
        }
        psum[i] = s;
      }
#pragma unroll
      for (int i = 0; i < 4; ++i) l_i[i] = l_i[i] * av[i] + row16_sum(psum[i]);
#pragma unroll
      for (int n0 = 0; n0 < 8; ++n0) Oacc[n0] *= av;
    }

    // P: C-layout -> LDS [row][key], read back as A-fragments.
    asm volatile("s_waitcnt lgkmcnt(0)" ::: "memory");  // WAR vs last iter's reads
#pragma unroll
    for (int nt = 0; nt < 4; ++nt)
#pragma unroll
      for (int i = 0; i < 4; ++i)
        pw[(Lq * 4 + i) * 72 + nt * 16 + Lm] = pf[nt][i];
    asm volatile("s_waitcnt lgkmcnt(0)" ::: "memory");  // RAW: writes visible

#pragma unroll
    for (int kc = 0; kc < 2; ++kc) {
      half8 afr = *(const half8*)(pw + Lm * 72 + kc * 32 + Lq * 8);
#pragma unroll
      for (int n0 = 0; n0 < 8; ++n0)
        Oacc[n0] = __builtin_amdgcn_mfma_f32_16x16x32_f16(afr, lvf[(n0 * 2 + kc) * 64 + L], Oacc[n0], 0, 0, 0);
    }
  };

  // kb ascends: block 0 always selected keeps m_i sane before masked blocks.
  for (int kb = 0; kb < qb; ++kb) {
    if (!((bm >> kb) & 1u)) continue;
    stage(kb);
    asm volatile("s_waitcnt vmcnt(0)" ::: "memory");
    __syncthreads();
    if ((un >> kb) & 1u) compute(kb, false);
    __syncthreads();
  }
  if ((bm >> qb) & 1u) {
    stage(qb);
    asm volatile("s_waitcnt vmcnt(0)" ::: "memory");
    __syncthreads();
    if ((un >> qb) & 1u) compute(qb, true);
  }

#pragma unroll
  for (int i = 0; i < 4; ++i) l_i[i] = 1.f / l_i[i];
  float* orow = out + (long)(t0 + m0 + Lq * 4) * 2048 + h * 128 + Lm;
#pragma unroll
  for (int i = 0; i < 4; ++i)
#pragma unroll
    for (int n0 = 0; n0 < 8; ++n0)
      orow[(long)i * 2048 + n0 * 16] = Oacc[n0][i] * l_i[i];
}

extern "C" void kernel_launch(void* const* d_in, const int* in_sizes, int n_in,
                              void* d_out, int out_size, void* d_ws, size_t ws_size,
                              hipStream_t stream) {
  const float* q = (const float*)d_in[0];
  const float* k = (const float*)d_in[1];
  const float* v = (const float*)d_in[2];
  const int* idx = (const int*)d_in[3];
  _Float16* kf = (_Float16*)d_ws;                       // 2048 blk * 12288 f16 = 50.3 MB
  _Float16* vf = kf + (size_t)2048 * 12288;             // 2048 blk * 8192  f16 = 33.6 MB
  float* out = (float*)d_out;
  kv_prep<<<2048, 256, 0, stream>>>(k, v, kf, vf);
  attn_main<<<2048, 256, 0, stream>>>(q, idx, kf, vf, out);
}